// Round 9
// baseline (42.003 us; speedup 1.0000x reference)
//
#include <hip/hip_runtime.h>

#define N_IN   256
#define N_EVAL 1088
#define TOTALW 1344
#define DEG    32

typedef __attribute__((ext_vector_type(8))) short short8;
typedef __attribute__((ext_vector_type(4))) float f32x4;
typedef unsigned short u16;
typedef unsigned int   u32;

__device__ __forceinline__ u32 pk2(float lo, float hi) {
    u32 ul = __float_as_uint(lo);
    u32 uh = __float_as_uint(hi);
    ul = (ul + 0x7fffu + ((ul >> 16) & 1u)) >> 16;
    uh = (uh + 0x7fffu + ((uh >> 16) & 1u)) & 0xffff0000u;
    return ul | uh;
}
__device__ __forceinline__ u16 bf1(float v) {
    u32 u = __float_as_uint(v);
    return (u16)((u + 0x7fffu + ((u >> 16) & 1u)) >> 16);
}

// ---------------- dense build: one thread per output u32 (2 bf16) ------------
__global__ __launch_bounds__(256) void build_dense32(
    const int* __restrict__ src, const float* __restrict__ w,
    u32* __restrict__ B32)
{
    const int t = blockIdx.x * 256 + threadIdx.x;    // 0..368639
    const int tile = t >> 8;                         // 0..1439
    const int q    = t & 255;
    const int lane = q >> 2;
    const int e2   = q & 3;
    int li, ts;
    if      (tile < 128)  { li = 0; ts = 0;    }
    else if (tile < 384)  { li = 1; ts = 128;  }
    else if (tile < 768)  { li = 2; ts = 384;  }
    else if (tile < 1280) { li = 3; ts = 768;  }
    else                  { li = 4; ts = 1280; }
    const int tloc = tile - ts;
    int kt, nt;
    if (li < 4) { kt = tloc >> 4; nt = tloc & 15; }
    else        { kt = tloc >> 2; nt = tloc & 3;  }
    const int ln = lane & 15, g = lane >> 4;
    const int gn = li * 256 + nt * 16 + ln;
    const int k0 = kt * 32 + g * 8 + e2 * 2;

    int c[DEG]; float ow[DEG];
    const int4*   s4 = (const int4*)(src + (size_t)gn * DEG);
    const float4* w4 = (const float4*)(w   + (size_t)gn * DEG);
    #pragma unroll
    for (int k = 0; k < 8; ++k) {
        int4 ci = s4[k]; float4 wf = w4[k];
        c[4*k+0]=ci.x; c[4*k+1]=ci.y; c[4*k+2]=ci.z; c[4*k+3]=ci.w;
        ow[4*k+0]=wf.x; ow[4*k+1]=wf.y; ow[4*k+2]=wf.z; ow[4*k+3]=wf.w;
    }
    float s0 = 0.f, s1 = 0.f;
    #pragma unroll
    for (int d = 0; d < DEG; ++d) {
        s0 += (c[d] == k0    ) ? ow[d] : 0.f;
        s1 += (c[d] == k0 + 1) ? ow[d] : 0.f;
    }
    B32[t] = pk2(s0, s1);
}

// ---------------- main MFMA kernel: TILE_B=64, 16 waves, 160 KiB LDS ----------
#define TILE_B 64
#define LDSCOLS 1280
#define RSTRIDE (LDSCOLS * 2)        // 2560 B/row, ≡ 0 mod 128 (bank-phase 0)

#define MFMA(a, b, c) __builtin_amdgcn_mfma_f32_16x16x32_bf16(a, b, c, 0, 0, 0)

__global__ __launch_bounds__(1024) void neat_mfma(
    const float* __restrict__ x, const u16* __restrict__ Bbuf,
    const float* __restrict__ bias, const float* __restrict__ resp,
    float* __restrict__ out)
{
    __shared__ uint4 ldsq[(TILE_B * RSTRIDE) / 16];   // 163,840 B (full pool)
    char* lds = (char*)ldsq;
    const int tid  = threadIdx.x;
    const int b0   = blockIdx.x * TILE_B;
    const int lane = tid & 63;
    const int wvid = tid >> 6;            // 0..15

    const int np = wvid & 7;              // n-pair: tiles np, np+8 (layers 0-3)
    const int mp = wvid >> 3;             // m-pair: tiles 2mp, 2mp+1

    const short8* Bf = (const short8*)Bbuf;
    // layer-0 B rings (depth 8, both streams) issued BEFORE the staging barrier
    short8 rp0[8], rp1[8];
    {
        const short8* bp0 = Bf + np * 64 + lane;             // li=0, nt=np
        const short8* bp1 = Bf + (np + 8) * 64 + lane;       // li=0, nt=np+8
        #pragma unroll
        for (int j = 0; j < 8; ++j) {
            rp0[j] = bp0[j * 1024];                          // STEP = 16*64
            rp1[j] = bp1[j * 1024];
        }
    }

    // stage x: f32 -> bf16, row-major, XOR-swizzled 16B granules
    #pragma unroll
    for (int i = 0; i < 4; ++i) {
        int f4 = tid + i * 1024;         // 4096 = 64 rows x 64 float4
        int row = f4 >> 6;
        int c4  = f4 & 63;
        float4 xv = ((const float4*)(x + (size_t)(b0 + row) * N_IN))[c4];
        u32 p0 = pk2(xv.x, xv.y), p1 = pk2(xv.z, xv.w);
        int byte = row * RSTRIDE + ((c4 * 8) ^ ((row & 7) << 4));
        *(u32*)(lds + byte)     = p0;
        *(u32*)(lds + byte + 4) = p1;
    }
    __syncthreads();

    const int r0  = lane & 15;
    const int g16 = (lane >> 4) << 4;
    const int sw  = (r0 & 7) << 4;
    const int ab0 = (r0 + mp * 32) * RSTRIDE;        // m-tile 2mp
    const int ab1 = (r0 + 16 + mp * 32) * RSTRIDE;   // m-tile 2mp+1

    int cbase = N_IN;
    #pragma unroll
    for (int li = 0; li < 5; ++li) {
        const int ktn = (N_IN + li * 256) >> 5;      // 8,16,24,32,40
        const int loff8[5] = {0, 8192, 24576, 49152, 81920};
        const int lo8 = loff8[li];
        const int nbase = cbase - N_IN;

        if (li < 4) {
            const int STEP = 16 * 64;                // NT=16
            const short8* bp0 = Bf + lo8 + np * 64 + lane;
            const short8* bp1 = Bf + lo8 + (np + 8) * 64 + lane;
            if (li != 0) {
                #pragma unroll
                for (int j = 0; j < 8; ++j) {
                    rp0[j] = bp0[j * STEP];
                    rp1[j] = bp1[j * STEP];
                }
            }
            const int gr0 = nbase + np * 16 + r0;
            const int gr1 = nbase + (np + 8) * 16 + r0;
            const float bb0 = bias[gr0], rr0 = resp[gr0];
            const float bb1 = bias[gr1], rr1 = resp[gr1];

            f32x4 acc00 = {0,0,0,0}, acc01 = {0,0,0,0};   // m0,m1 x nt=np
            f32x4 acc10 = {0,0,0,0}, acc11 = {0,0,0,0};   // m0,m1 x nt=np+8
            for (int kt8 = 0; kt8 < ktn; kt8 += 8) {
                #pragma unroll
                for (int j = 0; j < 8; ++j) {
                    int kt  = kt8 + j;
                    int ktp = kt + 8; if (ktp >= ktn) ktp = ktn - 1;
                    short8 f0 = bp0[ktp * STEP];
                    short8 f1 = bp1[ktp * STEP];
                    int inrow = (kt * 64 + g16) ^ sw;
                    short8 a0 = *(const short8*)(lds + ab0 + inrow);
                    short8 a1 = *(const short8*)(lds + ab1 + inrow);
                    acc00 = MFMA(a0, rp0[j], acc00);
                    acc01 = MFMA(a1, rp0[j], acc01);
                    acc10 = MFMA(a0, rp1[j], acc10);
                    acc11 = MFMA(a1, rp1[j], acc11);
                    rp0[j] = f0; rp1[j] = f1;
                }
            }
            #pragma unroll
            for (int t = 0; t < 2; ++t) {
                int nt = t ? (np + 8) : np;
                f32x4 aA = t ? acc10 : acc00;    // m-tile 2mp
                f32x4 aB = t ? acc11 : acc01;    // m-tile 2mp+1
                float bb = t ? bb1 : bb0;
                float rr = t ? rr1 : rr0;
                int colbyte = (cbase + nt * 16 + r0) * 2;
                #pragma unroll
                for (int r = 0; r < 4; ++r) {
                    int i0 = mp * 32 + ((lane >> 4) << 2) + r;
                    float v0 = fmaxf(fmaf(rr, aA[r], bb), 0.f);
                    *(u16*)(lds + i0 * RSTRIDE + (colbyte ^ ((i0 & 7) << 4))) = bf1(v0);
                    int i1 = i0 + 16;
                    float v1 = fmaxf(fmaf(rr, aB[r], bb), 0.f);
                    *(u16*)(lds + i1 * RSTRIDE + (colbyte ^ ((i1 & 7) << 4))) = bf1(v1);
                }
            }
            __syncthreads();
        } else {
            // layer 4: 64 neurons, ktn=40; 4 m-tiles x 4 n-tiles = 16 waves,
            // one (m,n) pair per wave, full K, direct global write.
            const int STEP = 4 * 64;                 // NT=4
            const int mt = wvid >> 2;
            const int nt = wvid & 3;
            const int ab = (r0 + mt * 16) * RSTRIDE;
            const short8* bp0 = Bf + lo8 + nt * 64 + lane;
            #pragma unroll
            for (int j = 0; j < 8; ++j) rp0[j] = bp0[j * STEP];
            const int gr0 = nbase + nt * 16 + r0;
            const float bb0 = bias[gr0], rr0 = resp[gr0];

            f32x4 acc0 = {0,0,0,0};
            for (int kt8 = 0; kt8 < 40; kt8 += 8) {
                #pragma unroll
                for (int j = 0; j < 8; ++j) {
                    int kt  = kt8 + j;
                    int ktp = kt + 8; if (ktp >= 40) ktp = 39;
                    short8 f0 = bp0[ktp * STEP];
                    int inrow = (kt * 64 + g16) ^ sw;
                    short8 a0 = *(const short8*)(lds + ab + inrow);
                    acc0 = MFMA(a0, rp0[j], acc0);
                    rp0[j] = f0;
                }
            }
            int col = nt * 16 + r0;
            #pragma unroll
            for (int r = 0; r < 4; ++r) {
                int i0 = mt * 16 + ((lane >> 4) << 2) + r;
                out[(size_t)(b0 + i0) * 64 + col] = fmaxf(fmaf(rr0, acc0[r], bb0), 0.f);
            }
        }
        cbase += 256;
    }
}

// ---------------- R4 fallback (LDS gather, proven) ----------------------------
#define FTILE_B 16
__device__ __forceinline__ int gbyte(int c, int h) {
    return ((c << 5) + (h << 4)) ^ (int)((((unsigned)c >> 2) & 7u) << 5);
}
__device__ __forceinline__ void fmadw(u32 d, float wv, float* acc) {
    acc[0] = fmaf(__uint_as_float(d << 16), wv, acc[0]);
    acc[1] = fmaf(__uint_as_float(d & 0xffff0000u), wv, acc[1]);
}
__device__ __forceinline__ void colacc16(const u32* vals, int c, float wv, float* acc) {
    const uint4* p = (const uint4*)((const char*)vals + gbyte(c, 0));
    uint4 a = p[0]; uint4 b = p[1];
    fmadw(a.x, wv, acc + 0);  fmadw(a.y, wv, acc + 2);
    fmadw(a.z, wv, acc + 4);  fmadw(a.w, wv, acc + 6);
    fmadw(b.x, wv, acc + 8);  fmadw(b.y, wv, acc + 10);
    fmadw(b.z, wv, acc + 12); fmadw(b.w, wv, acc + 14);
}
__global__ __launch_bounds__(256) void neat_eval_r4(
    const float* __restrict__ x, const float* __restrict__ w,
    const float* __restrict__ bias, const float* __restrict__ resp,
    const int* __restrict__ src, float* __restrict__ out)
{
    __shared__ u32 vals[TOTALW * 8];
    const int tid = threadIdx.x;
    const int b0  = blockIdx.x * FTILE_B;
    #pragma unroll
    for (int i = 0; i < 2; ++i) {
        int g = tid + i * 256;
        int c = g & 255, h = g >> 8;
        u32 pk[4];
        #pragma unroll
        for (int j = 0; j < 4; ++j) {
            float lo = x[(size_t)(b0 + h * 8 + 2 * j    ) * N_IN + c];
            float hi = x[(size_t)(b0 + h * 8 + 2 * j + 1) * N_IN + c];
            pk[j] = pk2(lo, hi);
        }
        *(uint4*)((char*)vals + gbyte(c, h)) = make_uint4(pk[0], pk[1], pk[2], pk[3]);
    }
    __syncthreads();
    int row = 0, outoff = N_IN;
    #pragma unroll
    for (int li = 0; li < 5; ++li) {
        const int sz = (li < 4) ? 256 : 64;
        for (int n = tid; n < sz; n += 256) {
            const int gr = row + n;
            const int4*   s4 = (const int4*)(src + (size_t)gr * DEG);
            const float4* w4 = (const float4*)(w   + (size_t)gr * DEG);
            float acc[16];
            #pragma unroll
            for (int i = 0; i < 16; ++i) acc[i] = 0.f;
            #pragma unroll
            for (int k = 0; k < DEG / 4; ++k) {
                int4 i4 = s4[k]; float4 wv = w4[k];
                colacc16(vals, i4.x, wv.x, acc);
                colacc16(vals, i4.y, wv.y, acc);
                colacc16(vals, i4.z, wv.z, acc);
                colacc16(vals, i4.w, wv.w, acc);
            }
            const float bb = bias[gr], rr = resp[gr];
            u32 pk[8];
            #pragma unroll
            for (int j = 0; j < 8; ++j) {
                float lo = fmaxf(fmaf(rr, acc[2 * j    ], bb), 0.f);
                float hi = fmaxf(fmaf(rr, acc[2 * j + 1], bb), 0.f);
                pk[j] = pk2(lo, hi);
            }
            int ob = gbyte(outoff + n, 0);
            *(uint4*)((char*)vals + ob)      = make_uint4(pk[0], pk[1], pk[2], pk[3]);
            *(uint4*)((char*)vals + ob + 16) = make_uint4(pk[4], pk[5], pk[6], pk[7]);
        }
        __syncthreads();
        row += sz; outoff += sz;
    }
    #pragma unroll
    for (int i = 0; i < 4; ++i) {
        int idx = tid + i * 256;
        int c = idx & 63, b = idx >> 6;
        int col = TOTALW - 64 + c;
        const u32* g = (const u32*)((const char*)vals + gbyte(col, b >> 3));
        u32 d = g[(b & 7) >> 1];
        float v = (b & 1) ? __uint_as_float(d & 0xffff0000u)
                          : __uint_as_float(d << 16);
        out[(size_t)(b0 + b) * 64 + c] = v;
    }
}

extern "C" void kernel_launch(void* const* d_in, const int* in_sizes, int n_in,
                              void* d_out, int out_size, void* d_ws, size_t ws_size,
                              hipStream_t stream) {
    const float* x    = (const float*)d_in[0];
    const float* w    = (const float*)d_in[1];
    const float* bias = (const float*)d_in[2];
    const float* resp = (const float*)d_in[3];
    const int*   src  = (const int*)d_in[4];
    float* out = (float*)d_out;

    const int batch = in_sizes[0] / N_IN;            // 8192
    const size_t need = 737280ull * 2;               // dense B, bf16

    if (ws_size >= need && (batch % TILE_B) == 0) {
        u32* Bbuf = (u32*)d_ws;
        build_dense32<<<1440, 256, 0, stream>>>(src, w, Bbuf);
        neat_mfma<<<batch / TILE_B, 1024, 0, stream>>>(x, (const u16*)Bbuf, bias, resp, out);
    } else {
        neat_eval_r4<<<batch / FTILE_B, 256, 0, stream>>>(x, w, bias, resp, src, out);
    }
}

// Round 10
// 39.049 us; speedup vs baseline: 1.0756x; 1.0756x over previous
//
#include <hip/hip_runtime.h>

#define N_IN   256
#define N_EVAL 1088
#define TOTALW 1344
#define DEG    32

typedef __attribute__((ext_vector_type(8))) short short8;
typedef __attribute__((ext_vector_type(4))) float f32x4;
typedef unsigned short u16;
typedef unsigned int   u32;

__device__ __forceinline__ u32 pk2(float lo, float hi) {
    u32 ul = __float_as_uint(lo);
    u32 uh = __float_as_uint(hi);
    ul = (ul + 0x7fffu + ((ul >> 16) & 1u)) >> 16;
    uh = (uh + 0x7fffu + ((uh >> 16) & 1u)) & 0xffff0000u;
    return ul | uh;
}
__device__ __forceinline__ u16 bf1(float v) {
    u32 u = __float_as_uint(v);
    return (u16)((u + 0x7fffu + ((u >> 16) & 1u)) >> 16);
}

// ---------------- dense build: one thread per output u32 (2 bf16) ------------
__global__ __launch_bounds__(256) void build_dense32(
    const int* __restrict__ src, const float* __restrict__ w,
    u32* __restrict__ B32)
{
    const int t = blockIdx.x * 256 + threadIdx.x;    // 0..368639
    const int tile = t >> 8;                         // 0..1439
    const int q    = t & 255;
    const int lane = q >> 2;
    const int e2   = q & 3;
    int li, ts;
    if      (tile < 128)  { li = 0; ts = 0;    }
    else if (tile < 384)  { li = 1; ts = 128;  }
    else if (tile < 768)  { li = 2; ts = 384;  }
    else if (tile < 1280) { li = 3; ts = 768;  }
    else                  { li = 4; ts = 1280; }
    const int tloc = tile - ts;
    int kt, nt;
    if (li < 4) { kt = tloc >> 4; nt = tloc & 15; }
    else        { kt = tloc >> 2; nt = tloc & 3;  }
    const int ln = lane & 15, g = lane >> 4;
    const int gn = li * 256 + nt * 16 + ln;
    const int k0 = kt * 32 + g * 8 + e2 * 2;

    int c[DEG]; float ow[DEG];
    const int4*   s4 = (const int4*)(src + (size_t)gn * DEG);
    const float4* w4 = (const float4*)(w   + (size_t)gn * DEG);
    #pragma unroll
    for (int k = 0; k < 8; ++k) {
        int4 ci = s4[k]; float4 wf = w4[k];
        c[4*k+0]=ci.x; c[4*k+1]=ci.y; c[4*k+2]=ci.z; c[4*k+3]=ci.w;
        ow[4*k+0]=wf.x; ow[4*k+1]=wf.y; ow[4*k+2]=wf.z; ow[4*k+3]=wf.w;
    }
    float s0 = 0.f, s1 = 0.f;
    #pragma unroll
    for (int d = 0; d < DEG; ++d) {
        s0 += (c[d] == k0    ) ? ow[d] : 0.f;
        s1 += (c[d] == k0 + 1) ? ow[d] : 0.f;
    }
    B32[t] = pk2(s0, s1);
}

// -------- main MFMA kernel: TILE_B=32, 16 waves (4/SIMD), grid=256 ------------
#define TILE_B 32
#define LDSCOLS 1280
#define RSTRIDE (LDSCOLS * 2)        // 2560 B/row

#define MFMA(a, b, c) __builtin_amdgcn_mfma_f32_16x16x32_bf16(a, b, c, 0, 0, 0)

__global__ __launch_bounds__(1024, 4) void neat_mfma(
    const float* __restrict__ x, const u16* __restrict__ Bbuf,
    const float* __restrict__ bias, const float* __restrict__ resp,
    float* __restrict__ out)
{
    __shared__ uint4 ldsq[(TILE_B * RSTRIDE) / 16];   // 81,920 B
    __shared__ f32x4 pbuf[8 * 64];                    // 8,192 B (layer-4 partials)
    char* lds = (char*)ldsq;
    const int tid  = threadIdx.x;
    const int b0   = blockIdx.x * TILE_B;
    const int lane = tid & 63;
    const int wvid = tid >> 6;            // 0..15

    const int np = wvid & 7;              // n-pair: tiles np, np+8 (layers 0-3)
    const int mt = wvid >> 3;             // m-tile 0/1 (rows mt*16..mt*16+15)

    const short8* Bf = (const short8*)Bbuf;
    // layer-0 B rings (depth 8, both streams) issued BEFORE the staging barrier
    short8 rp0[8], rp1[8];
    {
        const short8* bp0 = Bf + np * 64 + lane;             // li=0, nt=np
        const short8* bp1 = Bf + (np + 8) * 64 + lane;       // li=0, nt=np+8
        #pragma unroll
        for (int j = 0; j < 8; ++j) {
            rp0[j] = bp0[j * 1024];                          // STEP = 16*64
            rp1[j] = bp1[j * 1024];
        }
    }

    // stage x: f32 -> bf16, row-major, XOR-swizzled 16B granules
    #pragma unroll
    for (int i = 0; i < 2; ++i) {
        int f4 = tid + i * 1024;         // 2048 = 32 rows x 64 float4
        int row = f4 >> 6;
        int c4  = f4 & 63;
        float4 xv = ((const float4*)(x + (size_t)(b0 + row) * N_IN))[c4];
        u32 p0 = pk2(xv.x, xv.y), p1 = pk2(xv.z, xv.w);
        int byte = row * RSTRIDE + ((c4 * 8) ^ ((row & 7) << 4));
        *(u32*)(lds + byte)     = p0;
        *(u32*)(lds + byte + 4) = p1;
    }
    __syncthreads();

    const int r0  = lane & 15;
    const int g16 = (lane >> 4) << 4;
    const int sw  = (r0 & 7) << 4;
    const int ab  = (r0 + mt * 16) * RSTRIDE;

    int cbase = N_IN;
    #pragma unroll
    for (int li = 0; li < 5; ++li) {
        const int ktn = (N_IN + li * 256) >> 5;      // 8,16,24,32,40
        const int loff8[5] = {0, 8192, 24576, 49152, 81920};
        const int lo8 = loff8[li];
        const int nbase = cbase - N_IN;

        if (li < 4) {
            const int STEP = 16 * 64;                // NT=16
            const short8* bp0 = Bf + lo8 + np * 64 + lane;
            const short8* bp1 = Bf + lo8 + (np + 8) * 64 + lane;
            if (li != 0) {
                #pragma unroll
                for (int j = 0; j < 8; ++j) {
                    rp0[j] = bp0[j * STEP];
                    rp1[j] = bp1[j * STEP];
                }
            }
            const int gr0 = nbase + np * 16 + r0;
            const int gr1 = nbase + (np + 8) * 16 + r0;
            const float bb0 = bias[gr0], rr0 = resp[gr0];
            const float bb1 = bias[gr1], rr1 = resp[gr1];

            f32x4 acc0 = {0,0,0,0};                  // nt = np
            f32x4 acc1 = {0,0,0,0};                  // nt = np+8
            for (int kt8 = 0; kt8 < ktn; kt8 += 8) {
                #pragma unroll
                for (int j = 0; j < 8; ++j) {
                    int kt  = kt8 + j;
                    int ktp = kt + 8; if (ktp >= ktn) ktp = ktn - 1;
                    short8 f0 = bp0[ktp * STEP];
                    short8 f1 = bp1[ktp * STEP];
                    int inrow = (kt * 64 + g16) ^ sw;
                    short8 a = *(const short8*)(lds + ab + inrow);
                    acc0 = MFMA(a, rp0[j], acc0);
                    acc1 = MFMA(a, rp1[j], acc1);
                    rp0[j] = f0; rp1[j] = f1;
                }
            }
            #pragma unroll
            for (int t = 0; t < 2; ++t) {
                int nt = t ? (np + 8) : np;
                f32x4 aA = t ? acc1 : acc0;
                float bb = t ? bb1 : bb0;
                float rr = t ? rr1 : rr0;
                int colbyte = (cbase + nt * 16 + r0) * 2;
                #pragma unroll
                for (int r = 0; r < 4; ++r) {
                    int i0 = mt * 16 + ((lane >> 4) << 2) + r;
                    float v0 = fmaxf(fmaf(rr, aA[r], bb), 0.f);
                    *(u16*)(lds + i0 * RSTRIDE + (colbyte ^ ((i0 & 7) << 4))) = bf1(v0);
                }
            }
            __syncthreads();
        } else {
            // layer 4: 64 neurons, ktn=40. 16 waves = 2m x 4n x 2 K-segments.
            const int STEP = 4 * 64;                 // NT=4
            const int kseg = wvid >> 3;              // 0/1
            const int mt4  = (wvid >> 2) & 1;
            const int nt4  = wvid & 3;
            const int ab4  = (r0 + mt4 * 16) * RSTRIDE;
            const int ktbeg = kseg * 20;
            const int ktend = ktbeg + 20;
            const short8* bp0 = Bf + lo8 + nt4 * 64 + lane;
            #pragma unroll
            for (int j = 0; j < 4; ++j) rp0[j] = bp0[(ktbeg + j) * STEP];
            const int gr0 = nbase + nt4 * 16 + r0;
            const float bb0 = bias[gr0], rr0 = resp[gr0];

            f32x4 acc0 = {0,0,0,0};
            for (int kt4 = ktbeg; kt4 < ktend; kt4 += 4) {
                #pragma unroll
                for (int j = 0; j < 4; ++j) {
                    int kt  = kt4 + j;
                    int ktp = kt + 4; if (ktp >= ktend) ktp = ktend - 1;
                    short8 f0 = bp0[ktp * STEP];
                    int inrow = (kt * 64 + g16) ^ sw;
                    short8 a = *(const short8*)(lds + ab4 + inrow);
                    acc0 = MFMA(a, rp0[j], acc0);
                    rp0[j] = f0;
                }
            }
            if (kseg == 1)
                pbuf[(mt4 * 4 + nt4) * 64 + lane] = acc0;
            __syncthreads();
            if (kseg == 0) {
                acc0 += pbuf[(mt4 * 4 + nt4) * 64 + lane];
                int col = nt4 * 16 + r0;
                #pragma unroll
                for (int r = 0; r < 4; ++r) {
                    int i0 = mt4 * 16 + ((lane >> 4) << 2) + r;
                    out[(size_t)(b0 + i0) * 64 + col] = fmaxf(fmaf(rr0, acc0[r], bb0), 0.f);
                }
            }
        }
        cbase += 256;
    }
}

// ---------------- R4 fallback (LDS gather, proven) ----------------------------
#define FTILE_B 16
__device__ __forceinline__ int gbyte(int c, int h) {
    return ((c << 5) + (h << 4)) ^ (int)((((unsigned)c >> 2) & 7u) << 5);
}
__device__ __forceinline__ void fmadw(u32 d, float wv, float* acc) {
    acc[0] = fmaf(__uint_as_float(d << 16), wv, acc[0]);
    acc[1] = fmaf(__uint_as_float(d & 0xffff0000u), wv, acc[1]);
}
__device__ __forceinline__ void colacc16(const u32* vals, int c, float wv, float* acc) {
    const uint4* p = (const uint4*)((const char*)vals + gbyte(c, 0));
    uint4 a = p[0]; uint4 b = p[1];
    fmadw(a.x, wv, acc + 0);  fmadw(a.y, wv, acc + 2);
    fmadw(a.z, wv, acc + 4);  fmadw(a.w, wv, acc + 6);
    fmadw(b.x, wv, acc + 8);  fmadw(b.y, wv, acc + 10);
    fmadw(b.z, wv, acc + 12); fmadw(b.w, wv, acc + 14);
}
__global__ __launch_bounds__(256) void neat_eval_r4(
    const float* __restrict__ x, const float* __restrict__ w,
    const float* __restrict__ bias, const float* __restrict__ resp,
    const int* __restrict__ src, float* __restrict__ out)
{
    __shared__ u32 vals[TOTALW * 8];
    const int tid = threadIdx.x;
    const int b0  = blockIdx.x * FTILE_B;
    #pragma unroll
    for (int i = 0; i < 2; ++i) {
        int g = tid + i * 256;
        int c = g & 255, h = g >> 8;
        u32 pk[4];
        #pragma unroll
        for (int j = 0; j < 4; ++j) {
            float lo = x[(size_t)(b0 + h * 8 + 2 * j    ) * N_IN + c];
            float hi = x[(size_t)(b0 + h * 8 + 2 * j + 1) * N_IN + c];
            pk[j] = pk2(lo, hi);
        }
        *(uint4*)((char*)vals + gbyte(c, h)) = make_uint4(pk[0], pk[1], pk[2], pk[3]);
    }
    __syncthreads();
    int row = 0, outoff = N_IN;
    #pragma unroll
    for (int li = 0; li < 5; ++li) {
        const int sz = (li < 4) ? 256 : 64;
        for (int n = tid; n < sz; n += 256) {
            const int gr = row + n;
            const int4*   s4 = (const int4*)(src + (size_t)gr * DEG);
            const float4* w4 = (const float4*)(w   + (size_t)gr * DEG);
            float acc[16];
            #pragma unroll
            for (int i = 0; i < 16; ++i) acc[i] = 0.f;
            #pragma unroll
            for (int k = 0; k < DEG / 4; ++k) {
                int4 i4 = s4[k]; float4 wv = w4[k];
                colacc16(vals, i4.x, wv.x, acc);
                colacc16(vals, i4.y, wv.y, acc);
                colacc16(vals, i4.z, wv.z, acc);
                colacc16(vals, i4.w, wv.w, acc);
            }
            const float bb = bias[gr], rr = resp[gr];
            u32 pk[8];
            #pragma unroll
            for (int j = 0; j < 8; ++j) {
                float lo = fmaxf(fmaf(rr, acc[2 * j    ], bb), 0.f);
                float hi = fmaxf(fmaf(rr, acc[2 * j + 1], bb), 0.f);
                pk[j] = pk2(lo, hi);
            }
            int ob = gbyte(outoff + n, 0);
            *(uint4*)((char*)vals + ob)      = make_uint4(pk[0], pk[1], pk[2], pk[3]);
            *(uint4*)((char*)vals + ob + 16) = make_uint4(pk[4], pk[5], pk[6], pk[7]);
        }
        __syncthreads();
        row += sz; outoff += sz;
    }
    #pragma unroll
    for (int i = 0; i < 4; ++i) {
        int idx = tid + i * 256;
        int c = idx & 63, b = idx >> 6;
        int col = TOTALW - 64 + c;
        const u32* g = (const u32*)((const char*)vals + gbyte(col, b >> 3));
        u32 d = g[(b & 7) >> 1];
        float v = (b & 1) ? __uint_as_float(d & 0xffff0000u)
                          : __uint_as_float(d << 16);
        out[(size_t)(b0 + b) * 64 + c] = v;
    }
}

extern "C" void kernel_launch(void* const* d_in, const int* in_sizes, int n_in,
                              void* d_out, int out_size, void* d_ws, size_t ws_size,
                              hipStream_t stream) {
    const float* x    = (const float*)d_in[0];
    const float* w    = (const float*)d_in[1];
    const float* bias = (const float*)d_in[2];
    const float* resp = (const float*)d_in[3];
    const int*   src  = (const int*)d_in[4];
    float* out = (float*)d_out;

    const int batch = in_sizes[0] / N_IN;            // 8192
    const size_t need = 737280ull * 2;               // dense B, bf16

    if (ws_size >= need && (batch % TILE_B) == 0) {
        u32* Bbuf = (u32*)d_ws;
        build_dense32<<<1440, 256, 0, stream>>>(src, w, Bbuf);
        neat_mfma<<<batch / TILE_B, 1024, 0, stream>>>(x, (const u16*)Bbuf, bias, resp, out);
    } else {
        neat_eval_r4<<<batch / FTILE_B, 256, 0, stream>>>(x, w, bias, resp, src, out);
    }
}

// Round 11
// 27.397 us; speedup vs baseline: 1.5332x; 1.4253x over previous
//
#include <hip/hip_runtime.h>

#define N_IN   256
#define N_EVAL 1088
#define TOTALW 1344
#define DEG    32

typedef __attribute__((ext_vector_type(8))) short short8;
typedef __attribute__((ext_vector_type(4))) float f32x4;
typedef unsigned short u16;
typedef unsigned int   u32;

__device__ __forceinline__ u32 pk2(float lo, float hi) {
    u32 ul = __float_as_uint(lo);
    u32 uh = __float_as_uint(hi);
    ul = (ul + 0x7fffu + ((ul >> 16) & 1u)) >> 16;
    uh = (uh + 0x7fffu + ((uh >> 16) & 1u)) & 0xffff0000u;
    return ul | uh;
}
__device__ __forceinline__ u16 bf1(float v) {
    u32 u = __float_as_uint(v);
    return (u16)((u + 0x7fffu + ((u >> 16) & 1u)) >> 16);
}

// ---------------- dense build: one thread per output u32 (2 bf16) ------------
__global__ __launch_bounds__(256) void build_dense32(
    const int* __restrict__ src, const float* __restrict__ w,
    u32* __restrict__ B32)
{
    const int t = blockIdx.x * 256 + threadIdx.x;    // 0..368639
    const int tile = t >> 8;                         // 0..1439
    const int q    = t & 255;
    const int lane = q >> 2;
    const int e2   = q & 3;
    int li, ts;
    if      (tile < 128)  { li = 0; ts = 0;    }
    else if (tile < 384)  { li = 1; ts = 128;  }
    else if (tile < 768)  { li = 2; ts = 384;  }
    else if (tile < 1280) { li = 3; ts = 768;  }
    else                  { li = 4; ts = 1280; }
    const int tloc = tile - ts;
    int kt, nt;
    if (li < 4) { kt = tloc >> 4; nt = tloc & 15; }
    else        { kt = tloc >> 2; nt = tloc & 3;  }
    const int ln = lane & 15, g = lane >> 4;
    const int gn = li * 256 + nt * 16 + ln;
    const int k0 = kt * 32 + g * 8 + e2 * 2;

    int c[DEG]; float ow[DEG];
    const int4*   s4 = (const int4*)(src + (size_t)gn * DEG);
    const float4* w4 = (const float4*)(w   + (size_t)gn * DEG);
    #pragma unroll
    for (int k = 0; k < 8; ++k) {
        int4 ci = s4[k]; float4 wf = w4[k];
        c[4*k+0]=ci.x; c[4*k+1]=ci.y; c[4*k+2]=ci.z; c[4*k+3]=ci.w;
        ow[4*k+0]=wf.x; ow[4*k+1]=wf.y; ow[4*k+2]=wf.z; ow[4*k+3]=wf.w;
    }
    float s0 = 0.f, s1 = 0.f;
    #pragma unroll
    for (int d = 0; d < DEG; ++d) {
        s0 += (c[d] == k0    ) ? ow[d] : 0.f;
        s1 += (c[d] == k0 + 1) ? ow[d] : 0.f;
    }
    B32[t] = pk2(s0, s1);
}

// -------- main MFMA kernel: R8 structure + per-block K-rotation ---------------
#define TILE_B 32
#define LDSCOLS 1280
#define RSTRIDE (LDSCOLS * 2)        // 2560 B/row

#define MFMA(a, b, c) __builtin_amdgcn_mfma_f32_16x16x32_bf16(a, b, c, 0, 0, 0)

__global__ __launch_bounds__(512) void neat_mfma(
    const float* __restrict__ x, const u16* __restrict__ Bbuf,
    const float* __restrict__ bias, const float* __restrict__ resp,
    float* __restrict__ out)
{
    __shared__ uint4 ldsq[(TILE_B * RSTRIDE) / 16];   // 81,920 B
    __shared__ f32x4 pbuf[4 * 64 * 2];                // 8,192 B (layer-4 partials)
    char* lds = (char*)ldsq;
    const int tid  = threadIdx.x;
    const int bid  = blockIdx.x;
    const int b0   = bid * TILE_B;
    const int lane = tid & 63;
    const int wvid = tid >> 6;

    const short8* Bf = (const short8*)Bbuf;
    // layer-0 B rings (depth 8 = whole layer), rotated, issued pre-staging
    short8 rp0[8], rp1[8];
    {
        const int rot0 = bid & 7;                            // ktn0 = 8
        const short8* bp0 = Bf + wvid * 64 + lane;           // li=0, nt0=wvid
        const short8* bp1 = Bf + (wvid + 8) * 64 + lane;     // li=0, nt1=wvid+8
        #pragma unroll
        for (int j = 0; j < 8; ++j) {
            int ph = j + rot0; if (ph >= 8) ph -= 8;
            rp0[j] = bp0[ph * 1024];                         // STEP = 16*64
            rp1[j] = bp1[ph * 1024];
        }
    }

    // stage x: f32 -> bf16, row-major, XOR-swizzled 16B granules
    #pragma unroll
    for (int i = 0; i < 4; ++i) {
        int f4 = tid + i * 512;          // 2048 = 32 rows x 64 float4
        int row = f4 >> 6;
        int c4  = f4 & 63;
        float4 xv = ((const float4*)(x + (size_t)(b0 + row) * N_IN))[c4];
        u32 p0 = pk2(xv.x, xv.y), p1 = pk2(xv.z, xv.w);
        int byte = row * RSTRIDE + ((c4 * 8) ^ ((row & 7) << 4));
        *(u32*)(lds + byte)     = p0;
        *(u32*)(lds + byte + 4) = p1;
    }
    __syncthreads();

    const int r0  = lane & 15;
    const int g16 = (lane >> 4) << 4;
    const int sw  = (r0 & 7) << 4;
    const int ab0 = r0 * RSTRIDE;
    const int ab1 = (r0 + 16) * RSTRIDE;

    int cbase = N_IN;
    #pragma unroll
    for (int li = 0; li < 5; ++li) {
        const int ktn = (N_IN + li * 256) >> 5;      // 8,16,24,32,40
        const int loff8[5] = {0, 8192, 24576, 49152, 81920};
        const int lo8 = loff8[li];
        const int nbase = cbase - N_IN;

        if (li < 4) {
            const int STEP = 16 * 64;                // NT=16
            const int rot  = bid % ktn;
            const int nt0 = wvid, nt1 = wvid + 8;
            const short8* bp0 = Bf + lo8 + nt0 * 64 + lane;
            const short8* bp1 = Bf + lo8 + nt1 * 64 + lane;
            const int gr0 = nbase + nt0 * 16 + r0;
            const int gr1 = nbase + nt1 * 16 + r0;
            const float bb0 = bias[gr0], rr0 = resp[gr0];
            const float bb1 = bias[gr1], rr1 = resp[gr1];

            f32x4 acc00 = {0,0,0,0}, acc01 = {0,0,0,0};
            f32x4 acc10 = {0,0,0,0}, acc11 = {0,0,0,0};
            for (int kt8 = 0; kt8 < ktn; kt8 += 8) {
                #pragma unroll
                for (int j = 0; j < 8; ++j) {
                    int kt  = kt8 + j;
                    int ktp = kt + 8; if (ktp >= ktn) ktp = ktn - 1;
                    int php = ktp + rot; if (php >= ktn) php -= ktn;
                    short8 f0 = bp0[php * STEP];
                    short8 f1 = bp1[php * STEP];
                    int phk = kt + rot; if (phk >= ktn) phk -= ktn;
                    int inrow = (phk * 64 + g16) ^ sw;
                    short8 a0 = *(const short8*)(lds + ab0 + inrow);
                    short8 a1 = *(const short8*)(lds + ab1 + inrow);
                    acc00 = MFMA(a0, rp0[j], acc00);
                    acc01 = MFMA(a1, rp0[j], acc01);
                    acc10 = MFMA(a0, rp1[j], acc10);
                    acc11 = MFMA(a1, rp1[j], acc11);
                    rp0[j] = f0; rp1[j] = f1;
                }
            }

            // pre-issue NEXT layer's B ring before epilogue + barrier
            if (li < 3) {
                const int ktnN = (N_IN + (li + 1) * 256) >> 5;
                const int rotN = bid % ktnN;
                const short8* bn0 = Bf + loff8[li + 1] + nt0 * 64 + lane;
                const short8* bn1 = Bf + loff8[li + 1] + nt1 * 64 + lane;
                #pragma unroll
                for (int j = 0; j < 8; ++j) {
                    int ph = j + rotN; if (ph >= ktnN) ph -= ktnN;
                    rp0[j] = bn0[ph * STEP];
                    rp1[j] = bn1[ph * STEP];
                }
            } else {
                // li==3: pre-issue layer-4 depth-4 ring
                const int nt4   = wvid & 3;
                const int ktbg4 = (wvid >> 2) * 20;
                const int rot4  = bid % 20;
                const short8* b4 = Bf + loff8[4] + nt4 * 64 + lane;
                #pragma unroll
                for (int j = 0; j < 4; ++j) {
                    int ph = j + rot4; if (ph >= 20) ph -= 20;
                    rp0[j] = b4[(ktbg4 + ph) * 256];         // STEP4 = 4*64
                }
            }

            #pragma unroll
            for (int t = 0; t < 2; ++t) {
                int nt = t ? nt1 : nt0;
                f32x4 aA = t ? acc10 : acc00;    // rows 0..15
                f32x4 aB = t ? acc11 : acc01;    // rows 16..31
                float bb = t ? bb1 : bb0;
                float rr = t ? rr1 : rr0;
                int colbyte = (cbase + nt * 16 + r0) * 2;
                #pragma unroll
                for (int r = 0; r < 4; ++r) {
                    int i0 = ((lane >> 4) << 2) + r;
                    float v0 = fmaxf(fmaf(rr, aA[r], bb), 0.f);
                    *(u16*)(lds + i0 * RSTRIDE + (colbyte ^ ((i0 & 7) << 4))) = bf1(v0);
                    int i1 = i0 + 16;
                    float v1 = fmaxf(fmaf(rr, aB[r], bb), 0.f);
                    *(u16*)(lds + i1 * RSTRIDE + (colbyte ^ ((i1 & 7) << 4))) = bf1(v1);
                }
            }
            __syncthreads();
        } else {
            // layer 4: 64 neurons, ktn=40; nt = wvid&3, K split across wave quads
            const int STEP = 4 * 64;                 // NT=4
            const int nt0   = wvid & 3;
            const int ktbeg = (wvid >> 2) * 20;
            const int rot4  = bid % 20;
            const short8* bp0 = Bf + lo8 + nt0 * 64 + lane;
            const int gr0 = nbase + nt0 * 16 + r0;
            const float bb0 = bias[gr0], rr0 = resp[gr0];

            f32x4 acc0 = {0,0,0,0}, acc1 = {0,0,0,0};
            for (int kt4 = 0; kt4 < 20; kt4 += 4) {
                #pragma unroll
                for (int j = 0; j < 4; ++j) {
                    int lcl  = kt4 + j;
                    int lclp = lcl + 4; if (lclp >= 20) lclp = 19;
                    int php = lclp + rot4; if (php >= 20) php -= 20;
                    short8 f0 = bp0[(ktbeg + php) * STEP];
                    int phk = lcl + rot4; if (phk >= 20) phk -= 20;
                    int inrow = ((ktbeg + phk) * 64 + g16) ^ sw;
                    short8 a0 = *(const short8*)(lds + ab0 + inrow);
                    short8 a1 = *(const short8*)(lds + ab1 + inrow);
                    acc0 = MFMA(a0, rp0[j], acc0);
                    ac1:;
                    acc1 = MFMA(a1, rp0[j], acc1);
                    rp0[j] = f0;
                }
            }
            if (wvid >= 4) {
                pbuf[((wvid - 4) * 64 + lane) * 2 + 0] = acc0;
                pbuf[((wvid - 4) * 64 + lane) * 2 + 1] = acc1;
            }
            __syncthreads();
            if (wvid < 4) {
                f32x4 q0 = pbuf[(wvid * 64 + lane) * 2 + 0];
                f32x4 q1 = pbuf[(wvid * 64 + lane) * 2 + 1];
                acc0 += q0; acc1 += q1;
                int col = nt0 * 16 + r0;
                #pragma unroll
                for (int r = 0; r < 4; ++r) {
                    int i0 = ((lane >> 4) << 2) + r;
                    out[(size_t)(b0 + i0) * 64 + col] = fmaxf(fmaf(rr0, acc0[r], bb0), 0.f);
                    int i1 = i0 + 16;
                    out[(size_t)(b0 + i1) * 64 + col] = fmaxf(fmaf(rr0, acc1[r], bb0), 0.f);
                }
            }
        }
        cbase += 256;
    }
}

// ---------------- R4 fallback (LDS gather, proven) ----------------------------
#define FTILE_B 16
__device__ __forceinline__ int gbyte(int c, int h) {
    return ((c << 5) + (h << 4)) ^ (int)((((unsigned)c >> 2) & 7u) << 5);
}
__device__ __forceinline__ void fmadw(u32 d, float wv, float* acc) {
    acc[0] = fmaf(__uint_as_float(d << 16), wv, acc[0]);
    acc[1] = fmaf(__uint_as_float(d & 0xffff0000u), wv, acc[1]);
}
__device__ __forceinline__ void colacc16(const u32* vals, int c, float wv, float* acc) {
    const uint4* p = (const uint4*)((const char*)vals + gbyte(c, 0));
    uint4 a = p[0]; uint4 b = p[1];
    fmadw(a.x, wv, acc + 0);  fmadw(a.y, wv, acc + 2);
    fmadw(a.z, wv, acc + 4);  fmadw(a.w, wv, acc + 6);
    fmadw(b.x, wv, acc + 8);  fmadw(b.y, wv, acc + 10);
    fmadw(b.z, wv, acc + 12); fmadw(b.w, wv, acc + 14);
}
__global__ __launch_bounds__(256) void neat_eval_r4(
    const float* __restrict__ x, const float* __restrict__ w,
    const float* __restrict__ bias, const float* __restrict__ resp,
    const int* __restrict__ src, float* __restrict__ out)
{
    __shared__ u32 vals[TOTALW * 8];
    const int tid = threadIdx.x;
    const int b0  = blockIdx.x * FTILE_B;
    #pragma unroll
    for (int i = 0; i < 2; ++i) {
        int g = tid + i * 256;
        int c = g & 255, h = g >> 8;
        u32 pk[4];
        #pragma unroll
        for (int j = 0; j < 4; ++j) {
            float lo = x[(size_t)(b0 + h * 8 + 2 * j    ) * N_IN + c];
            float hi = x[(size_t)(b0 + h * 8 + 2 * j + 1) * N_IN + c];
            pk[j] = pk2(lo, hi);
        }
        *(uint4*)((char*)vals + gbyte(c, h)) = make_uint4(pk[0], pk[1], pk[2], pk[3]);
    }
    __syncthreads();
    int row = 0, outoff = N_IN;
    #pragma unroll
    for (int li = 0; li < 5; ++li) {
        const int sz = (li < 4) ? 256 : 64;
        for (int n = tid; n < sz; n += 256) {
            const int gr = row + n;
            const int4*   s4 = (const int4*)(src + (size_t)gr * DEG);
            const float4* w4 = (const float4*)(w   + (size_t)gr * DEG);
            float acc[16];
            #pragma unroll
            for (int i = 0; i < 16; ++i) acc[i] = 0.f;
            #pragma unroll
            for (int k = 0; k < DEG / 4; ++k) {
                int4 i4 = s4[k]; float4 wv = w4[k];
                colacc16(vals, i4.x, wv.x, acc);
                colacc16(vals, i4.y, wv.y, acc);
                colacc16(vals, i4.z, wv.z, acc);
                colacc16(vals, i4.w, wv.w, acc);
            }
            const float bb = bias[gr], rr = resp[gr];
            u32 pk[8];
            #pragma unroll
            for (int j = 0; j < 8; ++j) {
                float lo = fmaxf(fmaf(rr, acc[2 * j    ], bb), 0.f);
                float hi = fmaxf(fmaf(rr, acc[2 * j + 1], bb), 0.f);
                pk[j] = pk2(lo, hi);
            }
            int ob = gbyte(outoff + n, 0);
            *(uint4*)((char*)vals + ob)      = make_uint4(pk[0], pk[1], pk[2], pk[3]);
            *(uint4*)((char*)vals + ob + 16) = make_uint4(pk[4], pk[5], pk[6], pk[7]);
        }
        __syncthreads();
        row += sz; outoff += sz;
    }
    #pragma unroll
    for (int i = 0; i < 4; ++i) {
        int idx = tid + i * 256;
        int c = idx & 63, b = idx >> 6;
        int col = TOTALW - 64 + c;
        const u32* g = (const u32*)((const char*)vals + gbyte(col, b >> 3));
        u32 d = g[(b & 7) >> 1];
        float v = (b & 1) ? __uint_as_float(d & 0xffff0000u)
                          : __uint_as_float(d << 16);
        out[(size_t)(b0 + b) * 64 + c] = v;
    }
}

extern "C" void kernel_launch(void* const* d_in, const int* in_sizes, int n_in,
                              void* d_out, int out_size, void* d_ws, size_t ws_size,
                              hipStream_t stream) {
    const float* x    = (const float*)d_in[0];
    const float* w    = (const float*)d_in[1];
    const float* bias = (const float*)d_in[2];
    const float* resp = (const float*)d_in[3];
    const int*   src  = (const int*)d_in[4];
    float* out = (float*)d_out;

    const int batch = in_sizes[0] / N_IN;            // 8192
    const size_t need = 737280ull * 2;               // dense B, bf16

    if (ws_size >= need && (batch % TILE_B) == 0) {
        u32* Bbuf = (u32*)d_ws;
        build_dense32<<<1440, 256, 0, stream>>>(src, w, Bbuf);
        neat_mfma<<<batch / TILE_B, 512, 0, stream>>>(x, (const u16*)Bbuf, bias, resp, out);
    } else {
        neat_eval_r4<<<batch / FTILE_B, 256, 0, stream>>>(x, w, bias, resp, src, out);
    }
}